// Round 6
// baseline (730.714 us; speedup 1.0000x reference)
//
#include <hip/hip_runtime.h>
#include <hip/hip_bf16.h>

// R6: producer/consumer wave specialization in attn (512-thread blocks: waves 0-3
// compute S+softmax, waves 4-7 do PV with the O accumulator) so QK^T/softmax of
// tile jt overlaps PV of tile jt-1 -> critical path max(A,D)+C instead of A+C+D.
// Q-LDS re-read traffic halves (only S-waves read Q). Ps/fac double-buffered.
// proj upgraded to 128x128 tiles (16 MFMA/wave/kc-step).

typedef _Float16 f16;
typedef float f32x4 __attribute__((ext_vector_type(4)));
typedef _Float16 f16x8 __attribute__((ext_vector_type(8)));

#define MFMAH(A, B, C) __builtin_amdgcn_mfma_f32_16x16x32_f16((A), (B), (C), 0, 0, 0)

static constexpr int B_ = 8;
static constexpr int L_ = 2048;
static constexpr int D_ = 1024;
#define NEGF (-1e30f)

// ---------------- K0: transpose x[B][L][D] fp32 -> xT[B][D][L] f16 ----------------
__global__ __launch_bounds__(256) void transpose_kernel(const float* __restrict__ x,
                                                        f16* __restrict__ xT) {
  __shared__ f16 t[32][40];
  const int b = blockIdx.z;
  const int j0 = blockIdx.x << 5, d0 = blockIdx.y << 5;
  const int tid = threadIdx.x;
  const int r = tid >> 3, c = (tid & 7) << 2;
  float4 v = *(const float4*)&x[((size_t)(b * L_ + j0 + r)) * D_ + d0 + c];
  t[r][c + 0] = (f16)v.x; t[r][c + 1] = (f16)v.y;
  t[r][c + 2] = (f16)v.z; t[r][c + 3] = (f16)v.w;
  __syncthreads();
  union { f16 h[4]; uint2 u; } o;
  o.h[0] = t[c + 0][r]; o.h[1] = t[c + 1][r];
  o.h[2] = t[c + 2][r]; o.h[3] = t[c + 3][r];
  *(uint2*)&xT[((size_t)(b * D_ + d0 + r)) * L_ + j0 + c] = o.u;
}

// ---------------- K1: proj = relu(x @ W^T + b), f16 GEMM, 128x128 tile ----------------
__global__ __launch_bounds__(256) void proj_kernel(const float* __restrict__ x,
                                                   const float* __restrict__ W,
                                                   const float* __restrict__ bias,
                                                   f16* __restrict__ proj) {
  const int m0 = blockIdx.x << 7, n0 = blockIdx.y << 7;
  __shared__ f16 As[128 * 40], Bs[128 * 40];
  const int tid = threadIdx.x;
  const int wave = tid >> 6, lane = tid & 63;
  const int wr = wave >> 1, wc = wave & 1;  // 2x2 waves, each 64x64
  const int quad = lane >> 4, l16 = lane & 15;

  f32x4 acc[4][4];
#pragma unroll
  for (int mt = 0; mt < 4; ++mt)
#pragma unroll
    for (int nt = 0; nt < 4; ++nt) acc[mt][nt] = (f32x4){0.f, 0.f, 0.f, 0.f};

  for (int kc = 0; kc < D_; kc += 32) {
#pragma unroll
    for (int t = 0; t < 2; ++t) {
      const int task = tid + (t << 8);
      const int row = task >> 2, cg = (task & 3) << 3;
      float4 va = *(const float4*)&x[(size_t)(m0 + row) * D_ + kc + cg];
      float4 vb = *(const float4*)&x[(size_t)(m0 + row) * D_ + kc + cg + 4];
      union { f16 h[8]; uint4 u; } H;
      H.h[0] = (f16)va.x; H.h[1] = (f16)va.y; H.h[2] = (f16)va.z; H.h[3] = (f16)va.w;
      H.h[4] = (f16)vb.x; H.h[5] = (f16)vb.y; H.h[6] = (f16)vb.z; H.h[7] = (f16)vb.w;
      *(uint4*)&As[row * 40 + cg] = H.u;
      float4 wa = *(const float4*)&W[(size_t)(n0 + row) * D_ + kc + cg];
      float4 wb = *(const float4*)&W[(size_t)(n0 + row) * D_ + kc + cg + 4];
      H.h[0] = (f16)wa.x; H.h[1] = (f16)wa.y; H.h[2] = (f16)wa.z; H.h[3] = (f16)wa.w;
      H.h[4] = (f16)wb.x; H.h[5] = (f16)wb.y; H.h[6] = (f16)wb.z; H.h[7] = (f16)wb.w;
      *(uint4*)&Bs[row * 40 + cg] = H.u;
    }
    __syncthreads();
    f16x8 af[4], bf[4];
#pragma unroll
    for (int mt = 0; mt < 4; ++mt)
      af[mt] = *(const f16x8*)&As[(wr * 64 + mt * 16 + l16) * 40 + quad * 8];
#pragma unroll
    for (int nt = 0; nt < 4; ++nt)
      bf[nt] = *(const f16x8*)&Bs[(wc * 64 + nt * 16 + l16) * 40 + quad * 8];
#pragma unroll
    for (int mt = 0; mt < 4; ++mt)
#pragma unroll
      for (int nt = 0; nt < 4; ++nt) acc[mt][nt] = MFMAH(af[mt], bf[nt], acc[mt][nt]);
    __syncthreads();
  }
#pragma unroll
  for (int mt = 0; mt < 4; ++mt) {
#pragma unroll
    for (int nt = 0; nt < 4; ++nt) {
      const int n = n0 + wc * 64 + nt * 16 + l16;
      const float bv = bias[n];
#pragma unroll
      for (int r = 0; r < 4; ++r) {
        const int m = m0 + wr * 64 + mt * 16 + quad * 4 + r;
        proj[(size_t)m * D_ + n] = (f16)fmaxf(acc[mt][nt][r] + bv, 0.f);
      }
    }
  }
}

// ---------------- K2: fused flash attention, wave-specialized ----------------
// 512 threads: waves 0-3 produce P (QK^T+softmax), waves 4-7 consume (PV into acc).
// LDS = 66048 (Qs) + 9728 (Ss) + 9216 (Ps x2) + 640 = 85.5 KB -> 1 block/CU.
__global__ __launch_bounds__(512, 2) void attn_kernel(const f16* __restrict__ proj,
                                                      const f16* __restrict__ xT,
                                                      const int* __restrict__ xmask,
                                                      float* __restrict__ out) {
  const int b = blockIdx.x & 7;            // XCD-pinned batch
  const int i0 = (blockIdx.x >> 3) << 5;   // 32 query rows
  const int tid = threadIdx.x;
  const int wave = tid >> 6, lane = tid & 63;
  const int quad = lane >> 4, l16 = lane & 15;
  const bool is_s = (wave < 4);

  __shared__ f16 Qs[32 * 1032];
  __shared__ float Ss[32 * 76];
  __shared__ f16 Ps[2][32 * 72];
  __shared__ float fac_s[2][32];
  __shared__ float m_s[32], l_s[32];

  const f16* Qg = proj + ((size_t)(b * L_ + i0)) * D_;
#pragma unroll
  for (int idx = tid; idx < 32 * 128; idx += 512) {
    const int r = idx >> 7, c = (idx & 127) << 3;
    *(float4*)&Qs[r * 1032 + c] = *(const float4*)&Qg[(size_t)r * D_ + c];
  }
  if (tid < 32) { m_s[tid] = NEGF; l_s[tid] = 0.f; }

  f32x4 acc[2][16];  // PV-waves only: rows [mt*16+quad*4+r], cols [nbase+nt*16+l16]
#pragma unroll
  for (int mt = 0; mt < 2; ++mt)
#pragma unroll
    for (int nt = 0; nt < 16; ++nt) acc[mt][nt] = (f32x4){0.f, 0.f, 0.f, 0.f};

  __syncthreads();

  const f16* Xg = xT + (size_t)b * D_ * L_;
  const int nbase = (wave - 4) << 8;

  for (int jt = 0; jt <= 32; ++jt) {
    // ================= Interval X =================
    if (is_s) {
      if (jt < 32) {
        // ---- Phase A: S = Q K^T for keys [jt*64, +64), this wave's 16 keys ----
        const int j0 = jt << 6;
        const int jglob = j0 + (wave << 4) + l16;
        const bool masked = (xmask[b * L_ + jglob] != 0);
        f32x4 s0a = {0.f,0.f,0.f,0.f}, s0b = {0.f,0.f,0.f,0.f};
        f32x4 s1a = {0.f,0.f,0.f,0.f}, s1b = {0.f,0.f,0.f,0.f};
        const f16* Krow = proj + (size_t)(b * L_ + jglob) * D_;
        f16x8 k0 = *(const f16x8*)&Krow[quad * 8];
        f16x8 k1 = *(const f16x8*)&Krow[32 + quad * 8];
#pragma unroll
        for (int kc = 0; kc < D_; kc += 64) {
          f16x8 nk0, nk1;
          if (kc + 64 < D_) {
            nk0 = *(const f16x8*)&Krow[kc + 64 + quad * 8];
            nk1 = *(const f16x8*)&Krow[kc + 96 + quad * 8];
          }
          f16x8 qa0 = *(const f16x8*)&Qs[l16 * 1032 + kc + quad * 8];
          f16x8 qa1 = *(const f16x8*)&Qs[(16 + l16) * 1032 + kc + quad * 8];
          f16x8 qb0 = *(const f16x8*)&Qs[l16 * 1032 + kc + 32 + quad * 8];
          f16x8 qb1 = *(const f16x8*)&Qs[(16 + l16) * 1032 + kc + 32 + quad * 8];
          s0a = MFMAH(qa0, k0, s0a);
          s1a = MFMAH(qa1, k0, s1a);
          s0b = MFMAH(qb0, k1, s0b);
          s1b = MFMAH(qb1, k1, s1b);
          k0 = nk0; k1 = nk1;
        }
        // ---- Phase B: diag-zero, padding mask, stash S ----
#pragma unroll
        for (int mt = 0; mt < 2; ++mt) {
#pragma unroll
          for (int r = 0; r < 4; ++r) {
            const int irow = (mt << 4) + (quad << 2) + r;
            float v = mt ? (s1a[r] + s1b[r]) : (s0a[r] + s0b[r]);
            if (i0 + irow == jglob) v = 0.f;
            if (masked) v = NEGF;
            Ss[irow * 76 + (wave << 4) + l16] = v;
          }
        }
      }
    } else if (jt > 0) {
      // ---- Phase D: O = O*fac + P[jt-1] @ X ----
      const int pj = jt - 1;
      const int buf = pj & 1;
      const int j0 = pj << 6;
      float facr[2][4];
#pragma unroll
      for (int mt = 0; mt < 2; ++mt)
#pragma unroll
        for (int r = 0; r < 4; ++r) facr[mt][r] = fac_s[buf][(mt << 4) + (quad << 2) + r];
#pragma unroll
      for (int mt = 0; mt < 2; ++mt)
#pragma unroll
        for (int nt = 0; nt < 16; ++nt)
#pragma unroll
          for (int r = 0; r < 4; ++r) acc[mt][nt][r] *= facr[mt][r];

      f16x8 pa[2][2];
#pragma unroll
      for (int mt = 0; mt < 2; ++mt)
#pragma unroll
        for (int kt = 0; kt < 2; ++kt)
          pa[mt][kt] = *(const f16x8*)&Ps[buf][((mt << 4) + l16) * 72 + (kt << 5) + quad * 8];

      const f16* Xrow0 = Xg + (size_t)(nbase + l16) * L_ + j0;
      f16x8 xb0 = *(const f16x8*)&Xrow0[quad * 8];
      f16x8 xb1 = *(const f16x8*)&Xrow0[32 + quad * 8];
#pragma unroll
      for (int nt = 0; nt < 16; ++nt) {
        f16x8 nx0, nx1;
        if (nt + 1 < 16) {
          const f16* Xn = Xg + (size_t)(nbase + ((nt + 1) << 4) + l16) * L_ + j0;
          nx0 = *(const f16x8*)&Xn[quad * 8];
          nx1 = *(const f16x8*)&Xn[32 + quad * 8];
        }
        acc[0][nt] = MFMAH(pa[0][0], xb0, acc[0][nt]);
        acc[0][nt] = MFMAH(pa[0][1], xb1, acc[0][nt]);
        acc[1][nt] = MFMAH(pa[1][0], xb0, acc[1][nt]);
        acc[1][nt] = MFMAH(pa[1][1], xb1, acc[1][nt]);
        xb0 = nx0; xb1 = nx1;
      }
    }
    __syncthreads();

    // ================= Interval Y =================
    if (is_s && jt < 32) {
      // ---- Phase C: online softmax (8 threads/row, S-waves = 256 threads) ----
      const int row = tid >> 3, part = tid & 7;
      const float* srow = &Ss[row * 76 + (part << 3)];
      const float4 sA = *(const float4*)srow;
      const float4 sB = *(const float4*)(srow + 4);
      float mx = fmaxf(fmaxf(fmaxf(sA.x, sA.y), fmaxf(sA.z, sA.w)),
                       fmaxf(fmaxf(sB.x, sB.y), fmaxf(sB.z, sB.w)));
      mx = fmaxf(mx, __shfl_xor(mx, 1));
      mx = fmaxf(mx, __shfl_xor(mx, 2));
      mx = fmaxf(mx, __shfl_xor(mx, 4));
      const float m_old = m_s[row];
      const float m_new = fmaxf(m_old, mx);
      float p[8];
      p[0] = __expf(sA.x - m_new); p[1] = __expf(sA.y - m_new);
      p[2] = __expf(sA.z - m_new); p[3] = __expf(sA.w - m_new);
      p[4] = __expf(sB.x - m_new); p[5] = __expf(sB.y - m_new);
      p[6] = __expf(sB.z - m_new); p[7] = __expf(sB.w - m_new);
      float sum = ((p[0] + p[1]) + (p[2] + p[3])) + ((p[4] + p[5]) + (p[6] + p[7]));
      sum += __shfl_xor(sum, 1);
      sum += __shfl_xor(sum, 2);
      sum += __shfl_xor(sum, 4);
      const float fac = __expf(m_old - m_new);
      if (part == 0) {
        m_s[row] = m_new;
        l_s[row] = l_s[row] * fac + sum;
        fac_s[jt & 1][row] = fac;
      }
      union { f16 h[8]; uint4 u; } hp;
#pragma unroll
      for (int i = 0; i < 8; ++i) hp.h[i] = (f16)p[i];
      *(uint4*)&Ps[jt & 1][row * 72 + (part << 3)] = hp.u;
    }
    __syncthreads();
  }

  // ---- epilogue (PV waves): out = O / l ----
  if (!is_s) {
    float inv[2][4];
#pragma unroll
    for (int mt = 0; mt < 2; ++mt)
#pragma unroll
      for (int r = 0; r < 4; ++r) inv[mt][r] = 1.0f / l_s[(mt << 4) + (quad << 2) + r];
#pragma unroll
    for (int mt = 0; mt < 2; ++mt) {
#pragma unroll
      for (int nt = 0; nt < 16; ++nt) {
#pragma unroll
        for (int r = 0; r < 4; ++r) {
          const int row = i0 + (mt << 4) + (quad << 2) + r;
          const int col = nbase + (nt << 4) + l16;
          out[((size_t)(b * L_ + row)) * D_ + col] = acc[mt][nt][r] * inv[mt][r];
        }
      }
    }
  }
}

extern "C" void kernel_launch(void* const* d_in, const int* in_sizes, int n_in,
                              void* d_out, int out_size, void* d_ws, size_t ws_size,
                              hipStream_t stream) {
  const float* x = (const float*)d_in[0];
  const int* xmask = (const int*)d_in[1];
  const float* W = (const float*)d_in[2];
  const float* bias = (const float*)d_in[3];
  float* out = (float*)d_out;

  const size_t elems = (size_t)B_ * L_ * D_;
  if (ws_size < 2 * elems * sizeof(f16)) return;
  f16* proj = (f16*)d_ws;
  f16* xT = proj + elems;

  transpose_kernel<<<dim3(L_ / 32, D_ / 32, B_), 256, 0, stream>>>(x, xT);
  proj_kernel<<<dim3((B_ * L_) / 128, D_ / 128), 256, 0, stream>>>(x, W, bias, proj);
  attn_kernel<<<dim3((L_ / 32) * B_), 512, 0, stream>>>(proj, xT, xmask, out);
}